// Round 4
// baseline (1313.099 us; speedup 1.0000x reference)
//
#include <hip/hip_runtime.h>
#include <hip/hip_bf16.h>

// NEmbNet R4: batched-expert GEMMs. ws=512MiB (measured via poison fill) =>
// preconvert all weights+state to bf16 once, h0/h1 as [M][16*1024] interleaved,
// L1 = ONE GEMM [M,512]@[16384,512]^T, L2 = expert-folded grid, L3 = expert-
// folded softmax kernel. 8 launches total (was 50). GEMM core = R3's pipelined
// 4-phase/K-tile, triple-buffered LDS, counted vmcnt(6), XOR swizzle (passed 2x).

typedef short v8s __attribute__((ext_vector_type(8)));
typedef float v4f __attribute__((ext_vector_type(4)));
using bf16 = __hip_bfloat16;

#define AS_GLOBAL __attribute__((address_space(1)))
#define AS_LDS    __attribute__((address_space(3)))

static constexpr int Mtot = 8192;
static constexpr int Fdim = 512;
static constexpr int Hdim = 1024;
static constexpr int Pdim = 64;
static constexpr int Aexp = 16;
static constexpr int Ncat = Aexp * Hdim;  // 16384

__device__ __forceinline__ void gload_lds16(const void* g, void* l) {
  __builtin_amdgcn_global_load_lds((const AS_GLOBAL void*)g, (AS_LDS void*)l, 16, 0, 0);
}
__device__ __forceinline__ unsigned short bfu(float x) {
  bf16 h = __float2bfloat16(x);
  return *(unsigned short*)&h;
}
#define MFMA16(d, a, b) d = __builtin_amdgcn_mfma_f32_16x16x32_bf16(a, b, d, 0, 0, 0)
#define WAIT_VM6 asm volatile("s_waitcnt vmcnt(6)" ::: "memory")
#define WAIT_VM3 asm volatile("s_waitcnt vmcnt(3)" ::: "memory")
#define WAIT_VM0 asm volatile("s_waitcnt vmcnt(0)" ::: "memory")
#define WAIT_LGKM0 asm volatile("s_waitcnt lgkmcnt(0)" ::: "memory")
#define BAR() __builtin_amdgcn_s_barrier()

__device__ __forceinline__ void cvt_span(const float* __restrict__ src,
                                         unsigned short* __restrict__ dst, int n4,
                                         int gid, int nthr) {
  for (int i = gid; i < n4; i += nthr) {
    float4 v = ((const float4*)src)[i];
    ushort4 u;
    u.x = bfu(v.x); u.y = bfu(v.y); u.z = bfu(v.z); u.w = bfu(v.w);
    ((ushort4*)dst)[i] = u;
  }
}

// ---------------------------------------------------------------- cvt all inputs
__global__ void cvt_all_kernel(const float* __restrict__ s0, unsigned short* __restrict__ d0, int n0,
                               const float* __restrict__ s1, unsigned short* __restrict__ d1, int n1,
                               const float* __restrict__ s2, unsigned short* __restrict__ d2, int n2,
                               const float* __restrict__ s3, unsigned short* __restrict__ d3, int n3) {
  int gid = blockIdx.x * blockDim.x + threadIdx.x;
  int nthr = gridDim.x * blockDim.x;
  cvt_span(s0, d0, n0, gid, nthr);
  cvt_span(s1, d1, n1, gid, nthr);
  cvt_span(s2, d2, n2, gid, nthr);
  cvt_span(s3, d3, n3, gid, nthr);
}

// ---------------------------------------------------------------- identity fill
__global__ void ident_kernel(float* __restrict__ outp) {
  const long total4 = (long)Mtot * Pdim * Pdim / 4;
  long i = blockIdx.x * 256 + threadIdx.x;
  const long stride = (long)gridDim.x * 256;
  for (; i < total4; i += stride) {
    long e = i * 4;
    int q = (int)(e & 63);
    int p = (int)((e >> 6) & 63);
    float4 v;
    v.x = (p == q) ? 1.f : 0.f;
    v.y = (p == q + 1) ? 1.f : 0.f;
    v.z = (p == q + 2) ? 1.f : 0.f;
    v.w = (p == q + 3) ? 1.f : 0.f;
    *(float4*)&outp[e] = v;
  }
}

// ---------------------------------------------------------------- pipelined batched GEMM
// C[:, a*?+nIn*256+..] = relu(A @ B^T + bias). BM=128, BN=256, BK=64, 8 waves.
// Expert folded into grid.y: a = ny/NYE, nIn = ny%NYE. Triple-buffered LDS,
// 4 phases/K-tile, counted vmcnt(6), XOR col-swizzle (pre-swizzled global src).
template <int NT, int NYE>  // K = NT*64; NYE = n-tiles per expert
__global__ __launch_bounds__(512, 2) void gemm8p_kernel(
    const bf16* __restrict__ Ain, int Astride, int aAmul,
    const bf16* __restrict__ Bw, int aBmul,
    const float* __restrict__ bias, int aBiasMul,
    bf16* __restrict__ Cout, int Cstride, int aCmul) {
  constexpr int K = NT * 64;
  __shared__ short lsA[3][128 * 64];
  __shared__ short lsB[3][256 * 64];
  const int t = threadIdx.x;
  const int nbx = gridDim.x;
  const int nwg = gridDim.x * gridDim.y;
  const int flat = blockIdx.y * nbx + blockIdx.x;
  int swz = flat;
  if ((nwg & 7) == 0) {
    int q8 = nwg >> 3;
    swz = (flat & 7) * q8 + (flat >> 3);
  }
  const int mBase = (swz % nbx) * 128;  // bm fastest: same-XCD blocks share B panel
  const int ny = swz / nbx;
  const int a = ny / NYE, nIn = ny % NYE;
  const int nBase = nIn * 256;
  const bf16* Aexp2 = Ain + (size_t)a * aAmul;
  const bf16* Bexp = Bw + (size_t)a * aBmul;
  const float* biasE = bias + (size_t)a * aBiasMul + nBase;
  bf16* Cexp = Cout + (size_t)a * aCmul + nBase;

  const int w = t >> 6, lane = t & 63;
  const int wm = w >> 2, wn = w & 3;
  const int lr = lane & 15, lk = lane >> 4;

  const int srow = t >> 3;                  // 0..63
  const int sg = (t & 7) ^ ((t >> 3) & 7);  // swizzled col granule
  const bf16* gA = Aexp2 + (size_t)(mBase + srow) * Astride + sg * 8;
  const bf16* gB = Bexp + (size_t)(nBase + srow) * K + sg * 8;

  auto stageA = [&](short* buf, int i, int kt2) {
    gload_lds16(gA + (size_t)(i * 64) * Astride + kt2 * 64, buf + i * 4096 + t * 8);
  };
  auto stageB = [&](short* buf, int i, int kt2) {
    gload_lds16(gB + (size_t)(i * 64) * K + kt2 * 64, buf + i * 4096 + t * 8);
  };

  v4f acc[4][4];
#pragma unroll
  for (int m = 0; m < 4; ++m)
#pragma unroll
    for (int n = 0; n < 4; ++n) acc[m][n] = (v4f)(0.f);

  stageA(lsA[0], 0, 0); stageA(lsA[0], 1, 0);
  stageB(lsB[0], 0, 0); stageB(lsB[0], 1, 0); stageB(lsB[0], 2, 0); stageB(lsB[0], 3, 0);
  stageA(lsA[1], 0, 1); stageA(lsA[1], 1, 1);
  stageB(lsB[1], 0, 1); stageB(lsB[1], 1, 1); stageB(lsB[1], 2, 1); stageB(lsB[1], 3, 1);
  WAIT_VM6;
  BAR();

  int cb = 0, pb = 2;
  for (int kt = 0; kt < NT; ++kt) {
    const short* cA = lsA[cb];
    const short* cB = lsB[cb];
    short* pA = lsA[pb];
    short* pB = lsB[pb];
    const bool pf = (kt + 2) < NT;

    auto rdA = [&](int m, int s) -> v8s {
      int row = wm * 64 + m * 16 + lr;
      return *(const v8s*)&cA[row * 64 + ((((s << 2) + lk) ^ (row & 7)) << 3)];
    };
    auto rdB = [&](int n, int s) -> v8s {
      int row = wn * 64 + n * 16 + lr;
      return *(const v8s*)&cB[row * 64 + ((((s << 2) + lk) ^ (row & 7)) << 3)];
    };

    // P1: s=0, n={0,1}; stage A of kt+2
    v8s a0 = rdA(0, 0), a1 = rdA(1, 0), a2 = rdA(2, 0), a3 = rdA(3, 0);
    v8s b0 = rdB(0, 0), b1 = rdB(1, 0);
    if (pf) { stageA(pA, 0, kt + 2); stageA(pA, 1, kt + 2); }
    BAR(); WAIT_LGKM0;
    __builtin_amdgcn_s_setprio(1);
    MFMA16(acc[0][0], a0, b0); MFMA16(acc[1][0], a1, b0);
    MFMA16(acc[2][0], a2, b0); MFMA16(acc[3][0], a3, b0);
    MFMA16(acc[0][1], a0, b1); MFMA16(acc[1][1], a1, b1);
    MFMA16(acc[2][1], a2, b1); MFMA16(acc[3][1], a3, b1);
    __builtin_amdgcn_s_setprio(0);
    BAR();

    // P2: s=0, n={2,3}; stage B rounds 0,1
    v8s b2 = rdB(2, 0), b3 = rdB(3, 0);
    if (pf) { stageB(pB, 0, kt + 2); stageB(pB, 1, kt + 2); }
    BAR(); WAIT_LGKM0;
    __builtin_amdgcn_s_setprio(1);
    MFMA16(acc[0][2], a0, b2); MFMA16(acc[1][2], a1, b2);
    MFMA16(acc[2][2], a2, b2); MFMA16(acc[3][2], a3, b2);
    MFMA16(acc[0][3], a0, b3); MFMA16(acc[1][3], a1, b3);
    MFMA16(acc[2][3], a2, b3); MFMA16(acc[3][3], a3, b3);
    __builtin_amdgcn_s_setprio(0);
    BAR();

    // P3: s=1, n={0,1}; stage B rounds 2,3
    a0 = rdA(0, 1); a1 = rdA(1, 1); a2 = rdA(2, 1); a3 = rdA(3, 1);
    b0 = rdB(0, 1); b1 = rdB(1, 1);
    if (pf) { stageB(pB, 2, kt + 2); stageB(pB, 3, kt + 2); }
    BAR(); WAIT_LGKM0;
    __builtin_amdgcn_s_setprio(1);
    MFMA16(acc[0][0], a0, b0); MFMA16(acc[1][0], a1, b0);
    MFMA16(acc[2][0], a2, b0); MFMA16(acc[3][0], a3, b0);
    MFMA16(acc[0][1], a0, b1); MFMA16(acc[1][1], a1, b1);
    MFMA16(acc[2][1], a2, b1); MFMA16(acc[3][1], a3, b1);
    __builtin_amdgcn_s_setprio(0);
    BAR();

    // P4: s=1, n={2,3}; counted wait for next tile
    b2 = rdB(2, 1); b3 = rdB(3, 1);
    if (kt + 2 < NT) { WAIT_VM6; } else { WAIT_VM0; }
    BAR(); WAIT_LGKM0;
    __builtin_amdgcn_s_setprio(1);
    MFMA16(acc[0][2], a0, b2); MFMA16(acc[1][2], a1, b2);
    MFMA16(acc[2][2], a2, b2); MFMA16(acc[3][2], a3, b2);
    MFMA16(acc[0][3], a0, b3); MFMA16(acc[1][3], a1, b3);
    MFMA16(acc[2][3], a2, b3); MFMA16(acc[3][3], a3, b3);
    __builtin_amdgcn_s_setprio(0);
    BAR();

    cb = (cb == 2) ? 0 : cb + 1;
    pb = (pb == 2) ? 0 : pb + 1;
  }

#pragma unroll
  for (int n = 0; n < 4; ++n) {
    const int colIn = wn * 64 + n * 16 + lr;
    const float bv = biasE[colIn];
#pragma unroll
    for (int m = 0; m < 4; ++m) {
      const int row0 = mBase + wm * 64 + m * 16 + lk * 4;
#pragma unroll
      for (int j = 0; j < 4; ++j) {
        float v = acc[m][n][j] + bv;
        v = v > 0.f ? v : 0.f;
        Cexp[(size_t)(row0 + j) * Cstride + colIn] = __float2bfloat16(v);
      }
    }
  }
}

// ---------------------------------------------------------------- L3 + softmax + scatter
// grid (MC/32, 16): blockIdx.y = expert. X[32,64] = h1[:, a-slice] @ W2[a]^T + ltl[a].
__global__ __launch_bounds__(256) void gemm2_softmax_kernel(
    const bf16* __restrict__ h1, const bf16* __restrict__ W2b,
    const float* __restrict__ ltl, const int* __restrict__ lidx,
    const int* __restrict__ aidx, float* __restrict__ outp, int mGlobBase) {
  __shared__ short lsA[2][32 * 64];
  __shared__ short lsB[2][64 * 64];
  __shared__ float X[32][68];
  __shared__ int s_lidx[32];
  __shared__ int s_inv[64];
  __shared__ int s_arow;
  const int a = blockIdx.y;
  const bf16* Ain = h1 + (size_t)a * Hdim;
  const bf16* Bw = W2b + (size_t)a * Pdim * Hdim;
  const float* ltlE = ltl + (size_t)a * Pdim;

  const int t = threadIdx.x;
  const int mBase = blockIdx.x * 32;
  const int w = t >> 6, lane = t & 63;
  const int lr = lane & 15, lk = lane >> 4;
  const int wr = w & 1, wq = w >> 1;

  if (t < 64) s_inv[t] = -1;
  __syncthreads();
  if (t < 32) {
    int q = lidx[t];
    s_lidx[t] = q;
    s_inv[q] = t;
  }
  if (t == 0) s_arow = aidx[a];
  __syncthreads();

  const int srow = t >> 3;
  const int sg = (t & 7) ^ ((t >> 3) & 7);
  const bf16* gA = Ain + (size_t)(mBase + srow) * Ncat + sg * 8;
  const bf16* gB = Bw + (size_t)srow * Hdim + sg * 8;

  auto stage = [&](int buf, int kt) {
    gload_lds16(gA + kt * 64, &lsA[buf][t * 8]);
    gload_lds16(gB + kt * 64, &lsB[buf][t * 8]);
    gload_lds16(gB + (size_t)32 * Hdim + kt * 64, &lsB[buf][2048 + t * 8]);
  };

  v4f acc[2];
  acc[0] = (v4f)(0.f); acc[1] = (v4f)(0.f);

  stage(0, 0);
  for (int kt = 0; kt < 16; ++kt) {
    const int buf = kt & 1;
    if (kt + 1 < 16) { stage(buf ^ 1, kt + 1); WAIT_VM3; } else { WAIT_VM0; }
    BAR();
#pragma unroll
    for (int s = 0; s < 2; ++s) {
      int rowA = wr * 16 + lr;
      v8s af = *(const v8s*)&lsA[buf][rowA * 64 + ((((s << 2) + lk) ^ (rowA & 7)) << 3)];
#pragma unroll
      for (int n = 0; n < 2; ++n) {
        int rowB = wq * 32 + n * 16 + lr;
        v8s bf = *(const v8s*)&lsB[buf][rowB * 64 + ((((s << 2) + lk) ^ (rowB & 7)) << 3)];
        MFMA16(acc[n], af, bf);
      }
    }
    BAR();
  }

#pragma unroll
  for (int n = 0; n < 2; ++n) {
    const int col = wq * 32 + n * 16 + lr;
    const float lc = ltlE[col];
#pragma unroll
    for (int j = 0; j < 4; ++j) {
      X[wr * 16 + lk * 4 + j][col] = acc[n][j] + lc;
    }
  }
  __syncthreads();

  if (t < 32) {
    const int r = t;
    float mx = -1e30f;
#pragma unroll
    for (int l = 0; l < 32; ++l) mx = fmaxf(mx, X[r][s_lidx[l]]);
    float s = 0.f;
#pragma unroll
    for (int l = 0; l < 32; ++l) s += __expf(X[r][s_lidx[l]] - mx);
    const float rs = 1.f / s;
    const size_t obase = ((size_t)(mGlobBase + mBase + r) * 64 + s_arow) * 64;
#pragma unroll
    for (int q0 = 0; q0 < 64; q0 += 4) {
      float4 v;
      v.x = (s_inv[q0 + 0] >= 0) ? __expf(X[r][q0 + 0] - mx) * rs : 0.f;
      v.y = (s_inv[q0 + 1] >= 0) ? __expf(X[r][q0 + 1] - mx) * rs : 0.f;
      v.z = (s_inv[q0 + 2] >= 0) ? __expf(X[r][q0 + 2] - mx) * rs : 0.f;
      v.w = (s_inv[q0 + 3] >= 0) ? __expf(X[r][q0 + 3] - mx) * rs : 0.f;
      *(float4*)&outp[obase + q0] = v;
    }
  }
}

// ---------------------------------------------------------------- launch
extern "C" void kernel_launch(void* const* d_in, const int* in_sizes, int n_in,
                              void* d_out, int out_size, void* d_ws, size_t ws_size,
                              hipStream_t stream) {
  const float* state = (const float*)d_in[0];
  const float* W0 = (const float*)d_in[1];
  const float* b0 = (const float*)d_in[2];
  const float* W1 = (const float*)d_in[3];
  const float* b1 = (const float*)d_in[4];
  const float* W2 = (const float*)d_in[5];
  const float* ltl = (const float*)d_in[6];
  const int* lidx = (const int*)d_in[7];
  const int* aidx = (const int*)d_in[8];
  float* outp = (float*)d_out;

  // ws layout: stateb 8MiB | W0b 16MiB | W1b 32MiB | W2b 2MiB | h0 | h1
  char* ws = (char*)d_ws;
  bf16* stateb = (bf16*)ws;
  bf16* W0b = stateb + (size_t)Mtot * Fdim;
  bf16* W1b = W0b + (size_t)Aexp * Hdim * Fdim;
  bf16* W2b = W1b + (size_t)Aexp * Hdim * Hdim;
  bf16* h0 = W2b + (size_t)Aexp * Pdim * Hdim;
  const size_t fixedB = (size_t)(Mtot * Fdim + Aexp * Hdim * Fdim +
                                 Aexp * Hdim * Hdim + Aexp * Pdim * Hdim) * 2;
  int MC = 4096;  // chunk rows; h0+h1 = MC*64KiB
  while (MC > 128 && fixedB + (size_t)MC * 65536 + 4096 > ws_size) MC >>= 1;
  bf16* h1 = h0 + (size_t)MC * Ncat;

  ident_kernel<<<dim3(4096), dim3(256), 0, stream>>>(outp);
  cvt_all_kernel<<<dim3(2048), dim3(256), 0, stream>>>(
      state, (unsigned short*)stateb, Mtot * Fdim / 4,
      W0, (unsigned short*)W0b, Aexp * Hdim * Fdim / 4,
      W1, (unsigned short*)W1b, Aexp * Hdim * Hdim / 4,
      W2, (unsigned short*)W2b, Aexp * Pdim * Hdim / 4);

  for (int mOff = 0; mOff < Mtot; mOff += MC) {
    // L1: h0[MC,16384] = relu(state[MC,512] @ W0cat[16384,512]^T + b0cat)
    gemm8p_kernel<Fdim / 64, Ncat / 256><<<dim3(MC / 128, Ncat / 256), dim3(512), 0, stream>>>(
        stateb + (size_t)mOff * Fdim, Fdim, 0,
        W0b, 0,
        b0, 0,
        h0, Ncat, 0);
    // L2: h1[:, a*1024+..] = relu(h0[:, a*1024..] @ W1[a]^T + b1[a]), a folded
    gemm8p_kernel<Hdim / 64, Hdim / 256><<<dim3(MC / 128, Ncat / 256), dim3(512), 0, stream>>>(
        h0, Ncat, Hdim,
        W1b, Hdim * Hdim,
        b1, Hdim,
        h1, Ncat, Hdim);
    // L3 + softmax + scatter, expert folded into grid.y
    gemm2_softmax_kernel<<<dim3(MC / 32, Aexp), dim3(256), 0, stream>>>(
        h1, W2b, ltl, lidx, aidx, outp, mOff);
  }
}

// Round 5
// 756.216 us; speedup vs baseline: 1.7364x; 1.7364x over previous
//
#include <hip/hip_runtime.h>
#include <hip/hip_bf16.h>

// NEmbNet R5: revert GEMM core to proven m97 structure (128x128, BK=64, 4 waves,
// 32KB single-buffer LDS, 2 barriers/K-step -> ~3 blocks/CU TLP latency hiding).
// Keep batched launches. New: per-expert-contiguous h0/h1 ([A][MC][1024]),
// chunked-XCD + expert-supertile block ordering (per-XCD live set ~3MB < 4MB L2),
// MC=2048 chunks so h0/h1 (64MB) stay Infinity-Cache-resident between layers.

typedef short v8s __attribute__((ext_vector_type(8)));
typedef float v4f __attribute__((ext_vector_type(4)));
using bf16 = __hip_bfloat16;

#define AS_GLOBAL __attribute__((address_space(1)))
#define AS_LDS    __attribute__((address_space(3)))

static constexpr int Mtot = 8192;
static constexpr int Fdim = 512;
static constexpr int Hdim = 1024;
static constexpr int Pdim = 64;
static constexpr int Aexp = 16;

__device__ __forceinline__ void gload_lds16(const void* g, void* l) {
  __builtin_amdgcn_global_load_lds((const AS_GLOBAL void*)g, (AS_LDS void*)l, 16, 0, 0);
}
__device__ __forceinline__ unsigned short bfu(float x) {
  bf16 h = __float2bfloat16(x);
  return *(unsigned short*)&h;
}
#define MFMA16(d, a, b) d = __builtin_amdgcn_mfma_f32_16x16x32_bf16(a, b, d, 0, 0, 0)
#define WAIT_VM3 asm volatile("s_waitcnt vmcnt(3)" ::: "memory")
#define WAIT_VM0 asm volatile("s_waitcnt vmcnt(0)" ::: "memory")
#define BAR() __builtin_amdgcn_s_barrier()

__device__ __forceinline__ void cvt_span(const float* __restrict__ src,
                                         unsigned short* __restrict__ dst, int n4,
                                         int gid, int nthr) {
  for (int i = gid; i < n4; i += nthr) {
    float4 v = ((const float4*)src)[i];
    ushort4 u;
    u.x = bfu(v.x); u.y = bfu(v.y); u.z = bfu(v.z); u.w = bfu(v.w);
    ((ushort4*)dst)[i] = u;
  }
}

// ---------------------------------------------------------------- cvt all inputs
__global__ void cvt_all_kernel(const float* __restrict__ s0, unsigned short* __restrict__ d0, int n0,
                               const float* __restrict__ s1, unsigned short* __restrict__ d1, int n1,
                               const float* __restrict__ s2, unsigned short* __restrict__ d2, int n2,
                               const float* __restrict__ s3, unsigned short* __restrict__ d3, int n3) {
  int gid = blockIdx.x * blockDim.x + threadIdx.x;
  int nthr = gridDim.x * blockDim.x;
  cvt_span(s0, d0, n0, gid, nthr);
  cvt_span(s1, d1, n1, gid, nthr);
  cvt_span(s2, d2, n2, gid, nthr);
  cvt_span(s3, d3, n3, gid, nthr);
}

// ---------------------------------------------------------------- identity fill
__global__ void ident_kernel(float* __restrict__ outp) {
  const long total4 = (long)Mtot * Pdim * Pdim / 4;
  long i = blockIdx.x * 256 + threadIdx.x;
  const long stride = (long)gridDim.x * 256;
  for (; i < total4; i += stride) {
    long e = i * 4;
    int q = (int)(e & 63);
    int p = (int)((e >> 6) & 63);
    float4 v;
    v.x = (p == q) ? 1.f : 0.f;
    v.y = (p == q + 1) ? 1.f : 0.f;
    v.z = (p == q + 2) ? 1.f : 0.f;
    v.w = (p == q + 3) ? 1.f : 0.f;
    *(float4*)&outp[e] = v;
  }
}

// ---------------------------------------------------------------- m97-style batched GEMM
// C[g-slice] = relu(A @ B^T + bias). 128x128 tile, BK=64, 4 waves, 256 thr.
// N is organized as 16 groups of 1024 cols (group = expert or W0cat slice).
// Block ordering: chunked XCD swizzle, then group -> msuper(4) -> ny(8) -> mloc(4)
// so each XCD's live set is A 1MB + B 2MB (fits 4MB L2).
template <int NT>  // K = NT*64
__global__ __launch_bounds__(256) void gemm97_kernel(
    const bf16* __restrict__ Ain, long aAmul,
    const bf16* __restrict__ Bw,
    const float* __restrict__ bias,
    bf16* __restrict__ Cout, long aCmul, int nbm) {
  constexpr int K = NT * 64;
  __shared__ short lsA[128 * 64];
  __shared__ short lsB[128 * 64];
  const int t = threadIdx.x;
  const int nwg = nbm * 128;  // nbm * 8 ny * 16 groups

  // chunked XCD swizzle: XCD x runs swz range [x*perx, (x+1)*perx) in order
  const int flat = blockIdx.x;
  const int perx = nwg >> 3;
  const int swz = (flat & 7) * perx + (flat >> 3);
  // supertile decode: group outer, msuper(4 m-tiles), ny(8), mlocal(4)
  const int perg = nbm * 8;
  const int g = swz / perg;
  const int e = swz % perg;
  const int msup = e >> 5;          // e / 32
  const int ny = (e >> 2) & 7;
  const int mloc = e & 3;
  const int mBase = (msup * 4 + mloc) * 128;
  const int nBase = ny * 128;

  const bf16* A0 = Ain + (size_t)g * aAmul;
  const bf16* B0 = Bw + (size_t)g * (1024 * K);
  const float* biasE = bias + g * 1024 + nBase;
  bf16* C0 = Cout + (size_t)g * aCmul + nBase;

  const int w = t >> 6, lane = t & 63;
  const int wm = w >> 1, wn = w & 1;
  const int lr = lane & 15, lk = lane >> 4;

  v4f acc[4][4];
#pragma unroll
  for (int m = 0; m < 4; ++m)
#pragma unroll
    for (int n = 0; n < 4; ++n) acc[m][n] = (v4f)(0.f);

  const int rowA = t >> 3;        // 0..31
  const int col8 = (t & 7) * 8;   // element col within BK
  const bf16* gA = A0 + (size_t)(mBase + rowA) * K + col8;
  const bf16* gB = B0 + (size_t)(nBase + rowA) * K + col8;

  for (int k0 = 0; k0 < K; k0 += 64) {
#pragma unroll
    for (int i = 0; i < 4; ++i) {
      gload_lds16(gA + (size_t)(i * 32) * K + k0, &lsA[i * 2048 + t * 8]);
      gload_lds16(gB + (size_t)(i * 32) * K + k0, &lsB[i * 2048 + t * 8]);
    }
    __syncthreads();
#pragma unroll
    for (int kk = 0; kk < 2; ++kk) {
      v8s af[4], bfr[4];
#pragma unroll
      for (int m = 0; m < 4; ++m)
        af[m] = *(const v8s*)&lsA[(wm * 64 + m * 16 + lr) * 64 + kk * 32 + lk * 8];
#pragma unroll
      for (int n = 0; n < 4; ++n)
        bfr[n] = *(const v8s*)&lsB[(wn * 64 + n * 16 + lr) * 64 + kk * 32 + lk * 8];
#pragma unroll
      for (int m = 0; m < 4; ++m)
#pragma unroll
        for (int n = 0; n < 4; ++n)
          MFMA16(acc[m][n], af[m], bfr[n]);
    }
    __syncthreads();
  }

#pragma unroll
  for (int n = 0; n < 4; ++n) {
    const int colIn = wn * 64 + n * 16 + lr;
    const float bv = biasE[colIn];
#pragma unroll
    for (int m = 0; m < 4; ++m) {
      const int row0 = mBase + wm * 64 + m * 16 + lk * 4;
#pragma unroll
      for (int j = 0; j < 4; ++j) {
        float v = acc[m][n][j] + bv;
        v = v > 0.f ? v : 0.f;
        C0[(size_t)(row0 + j) * 1024 + colIn] = __float2bfloat16(v);
      }
    }
  }
}

// ---------------------------------------------------------------- L3 + softmax + scatter
// grid (MC/32, 16): blockIdx.y = expert. h1 per-expert contiguous [A][MC][1024].
__global__ __launch_bounds__(256) void gemm2_softmax_kernel(
    const bf16* __restrict__ h1, const bf16* __restrict__ W2b,
    const float* __restrict__ ltl, const int* __restrict__ lidx,
    const int* __restrict__ aidx, float* __restrict__ outp, int mGlobBase, int MC) {
  __shared__ short lsA[2][32 * 64];
  __shared__ short lsB[2][64 * 64];
  __shared__ float X[32][68];
  __shared__ int s_lidx[32];
  __shared__ int s_inv[64];
  __shared__ int s_arow;
  const int a = blockIdx.y;
  const bf16* Ain = h1 + (size_t)a * MC * Hdim;
  const bf16* Bw = W2b + (size_t)a * Pdim * Hdim;
  const float* ltlE = ltl + (size_t)a * Pdim;

  const int t = threadIdx.x;
  const int mBase = blockIdx.x * 32;
  const int w = t >> 6, lane = t & 63;
  const int lr = lane & 15, lk = lane >> 4;
  const int wr = w & 1, wq = w >> 1;

  if (t < 64) s_inv[t] = -1;
  __syncthreads();
  if (t < 32) {
    int q = lidx[t];
    s_lidx[t] = q;
    s_inv[q] = t;
  }
  if (t == 0) s_arow = aidx[a];
  __syncthreads();

  const int srow = t >> 3;
  const int sg = (t & 7) ^ ((t >> 3) & 7);
  const bf16* gA = Ain + (size_t)(mBase + srow) * Hdim + sg * 8;
  const bf16* gB = Bw + (size_t)srow * Hdim + sg * 8;

  auto stage = [&](int buf, int kt) {
    gload_lds16(gA + kt * 64, &lsA[buf][t * 8]);
    gload_lds16(gB + kt * 64, &lsB[buf][t * 8]);
    gload_lds16(gB + (size_t)32 * Hdim + kt * 64, &lsB[buf][2048 + t * 8]);
  };

  v4f acc[2];
  acc[0] = (v4f)(0.f); acc[1] = (v4f)(0.f);

  stage(0, 0);
  for (int kt = 0; kt < 16; ++kt) {
    const int buf = kt & 1;
    if (kt + 1 < 16) { stage(buf ^ 1, kt + 1); WAIT_VM3; } else { WAIT_VM0; }
    BAR();
#pragma unroll
    for (int s = 0; s < 2; ++s) {
      int rowA = wr * 16 + lr;
      v8s af = *(const v8s*)&lsA[buf][rowA * 64 + ((((s << 2) + lk) ^ (rowA & 7)) << 3)];
#pragma unroll
      for (int n = 0; n < 2; ++n) {
        int rowB = wq * 32 + n * 16 + lr;
        v8s bf = *(const v8s*)&lsB[buf][rowB * 64 + ((((s << 2) + lk) ^ (rowB & 7)) << 3)];
        MFMA16(acc[n], af, bf);
      }
    }
    BAR();
  }

#pragma unroll
  for (int n = 0; n < 2; ++n) {
    const int col = wq * 32 + n * 16 + lr;
    const float lc = ltlE[col];
#pragma unroll
    for (int j = 0; j < 4; ++j) {
      X[wr * 16 + lk * 4 + j][col] = acc[n][j] + lc;
    }
  }
  __syncthreads();

  if (t < 32) {
    const int r = t;
    float mx = -1e30f;
#pragma unroll
    for (int l = 0; l < 32; ++l) mx = fmaxf(mx, X[r][s_lidx[l]]);
    float s = 0.f;
#pragma unroll
    for (int l = 0; l < 32; ++l) s += __expf(X[r][s_lidx[l]] - mx);
    const float rs = 1.f / s;
    const size_t obase = ((size_t)(mGlobBase + mBase + r) * 64 + s_arow) * 64;
#pragma unroll
    for (int q0 = 0; q0 < 64; q0 += 4) {
      float4 v;
      v.x = (s_inv[q0 + 0] >= 0) ? __expf(X[r][q0 + 0] - mx) * rs : 0.f;
      v.y = (s_inv[q0 + 1] >= 0) ? __expf(X[r][q0 + 1] - mx) * rs : 0.f;
      v.z = (s_inv[q0 + 2] >= 0) ? __expf(X[r][q0 + 2] - mx) * rs : 0.f;
      v.w = (s_inv[q0 + 3] >= 0) ? __expf(X[r][q0 + 3] - mx) * rs : 0.f;
      *(float4*)&outp[obase + q0] = v;
    }
  }
}

// ---------------------------------------------------------------- launch
extern "C" void kernel_launch(void* const* d_in, const int* in_sizes, int n_in,
                              void* d_out, int out_size, void* d_ws, size_t ws_size,
                              hipStream_t stream) {
  const float* state = (const float*)d_in[0];
  const float* W0 = (const float*)d_in[1];
  const float* b0 = (const float*)d_in[2];
  const float* W1 = (const float*)d_in[3];
  const float* b1 = (const float*)d_in[4];
  const float* W2 = (const float*)d_in[5];
  const float* ltl = (const float*)d_in[6];
  const int* lidx = (const int*)d_in[7];
  const int* aidx = (const int*)d_in[8];
  float* outp = (float*)d_out;

  // ws: stateb 8MiB | W0b 16 | W1b 32 | W2b 2 | h0 | h1  (h = Aexp*MC*1024*2B each)
  char* ws = (char*)d_ws;
  bf16* stateb = (bf16*)ws;
  bf16* W0b = stateb + (size_t)Mtot * Fdim;
  bf16* W1b = W0b + (size_t)Aexp * Hdim * Fdim;
  bf16* W2b = W1b + (size_t)Aexp * Hdim * Hdim;
  bf16* h0 = W2b + (size_t)Aexp * Pdim * Hdim;
  const size_t fixedB = (size_t)(Mtot * Fdim + Aexp * Hdim * Fdim +
                                 Aexp * Hdim * Hdim + Aexp * Pdim * Hdim) * 2;
  int MC = 2048;  // h0/h1 = 64MiB each -> L3-resident between layers
  while (MC > 512 && fixedB + (size_t)2 * Aexp * MC * Hdim * 2 + 4096 > ws_size) MC >>= 1;
  bf16* h1 = h0 + (size_t)Aexp * MC * Hdim;

  ident_kernel<<<dim3(4096), dim3(256), 0, stream>>>(outp);
  cvt_all_kernel<<<dim3(2048), dim3(256), 0, stream>>>(
      state, (unsigned short*)stateb, Mtot * Fdim / 4,
      W0, (unsigned short*)W0b, Aexp * Hdim * Fdim / 4,
      W1, (unsigned short*)W1b, Aexp * Hdim * Hdim / 4,
      W2, (unsigned short*)W2b, Aexp * Pdim * Hdim / 4);

  const int nbm = MC / 128;
  for (int mOff = 0; mOff < Mtot; mOff += MC) {
    // L1: h0[a][MC][1024] = relu(state[MC,512] @ W0[a][1024,512]^T + b0[a])
    gemm97_kernel<Fdim / 64><<<dim3(nbm * 128), dim3(256), 0, stream>>>(
        stateb + (size_t)mOff * Fdim, 0L,
        W0b, b0, h0, (long)MC * Hdim, nbm);
    // L2: h1[a][MC][1024] = relu(h0[a] @ W1[a][1024,1024]^T + b1[a])
    gemm97_kernel<Hdim / 64><<<dim3(nbm * 128), dim3(256), 0, stream>>>(
        h0, (long)MC * Hdim,
        W1b, b1, h1, (long)MC * Hdim, nbm);
    // L3 + softmax + scatter
    gemm2_softmax_kernel<<<dim3(MC / 32, Aexp), dim3(256), 0, stream>>>(
        h1, W2b, ltl, lidx, aidx, outp, mOff, MC);
  }
}

// Round 6
// 622.526 us; speedup vs baseline: 2.1093x; 1.2148x over previous
//
#include <hip/hip_runtime.h>
#include <hip/hip_bf16.h>

// NEmbNet R6: R5 + T2 both-sides XOR swizzle on gemm97's LDS tiles.
// R5 diagnosis: 2.5e7 bank-conflict cycles/dispatch (~24 cyc extra per
// ds_read_b128) made the LDS read pipe the critical path (MfmaUtil capped 25%).
// Swizzle: global source granule sg=(t&7)^(row&7) (LDS dest linear, required by
// global_load_lds), read granule (kk*4+lk)^(row&7). Same pattern as gemm2 (proven).

typedef short v8s __attribute__((ext_vector_type(8)));
typedef float v4f __attribute__((ext_vector_type(4)));
using bf16 = __hip_bfloat16;

#define AS_GLOBAL __attribute__((address_space(1)))
#define AS_LDS    __attribute__((address_space(3)))

static constexpr int Mtot = 8192;
static constexpr int Fdim = 512;
static constexpr int Hdim = 1024;
static constexpr int Pdim = 64;
static constexpr int Aexp = 16;

__device__ __forceinline__ void gload_lds16(const void* g, void* l) {
  __builtin_amdgcn_global_load_lds((const AS_GLOBAL void*)g, (AS_LDS void*)l, 16, 0, 0);
}
__device__ __forceinline__ unsigned short bfu(float x) {
  bf16 h = __float2bfloat16(x);
  return *(unsigned short*)&h;
}
#define MFMA16(d, a, b) d = __builtin_amdgcn_mfma_f32_16x16x32_bf16(a, b, d, 0, 0, 0)
#define WAIT_VM3 asm volatile("s_waitcnt vmcnt(3)" ::: "memory")
#define WAIT_VM0 asm volatile("s_waitcnt vmcnt(0)" ::: "memory")
#define BAR() __builtin_amdgcn_s_barrier()

__device__ __forceinline__ void cvt_span(const float* __restrict__ src,
                                         unsigned short* __restrict__ dst, int n4,
                                         int gid, int nthr) {
  for (int i = gid; i < n4; i += nthr) {
    float4 v = ((const float4*)src)[i];
    ushort4 u;
    u.x = bfu(v.x); u.y = bfu(v.y); u.z = bfu(v.z); u.w = bfu(v.w);
    ((ushort4*)dst)[i] = u;
  }
}

// ---------------------------------------------------------------- cvt all inputs
__global__ void cvt_all_kernel(const float* __restrict__ s0, unsigned short* __restrict__ d0, int n0,
                               const float* __restrict__ s1, unsigned short* __restrict__ d1, int n1,
                               const float* __restrict__ s2, unsigned short* __restrict__ d2, int n2,
                               const float* __restrict__ s3, unsigned short* __restrict__ d3, int n3) {
  int gid = blockIdx.x * blockDim.x + threadIdx.x;
  int nthr = gridDim.x * blockDim.x;
  cvt_span(s0, d0, n0, gid, nthr);
  cvt_span(s1, d1, n1, gid, nthr);
  cvt_span(s2, d2, n2, gid, nthr);
  cvt_span(s3, d3, n3, gid, nthr);
}

// ---------------------------------------------------------------- identity fill
__global__ void ident_kernel(float* __restrict__ outp) {
  const long total4 = (long)Mtot * Pdim * Pdim / 4;
  long i = blockIdx.x * 256 + threadIdx.x;
  const long stride = (long)gridDim.x * 256;
  for (; i < total4; i += stride) {
    long e = i * 4;
    int q = (int)(e & 63);
    int p = (int)((e >> 6) & 63);
    float4 v;
    v.x = (p == q) ? 1.f : 0.f;
    v.y = (p == q + 1) ? 1.f : 0.f;
    v.z = (p == q + 2) ? 1.f : 0.f;
    v.w = (p == q + 3) ? 1.f : 0.f;
    *(float4*)&outp[e] = v;
  }
}

// ---------------------------------------------------------------- m97-style batched GEMM + T2 swizzle
// C[g-slice] = relu(A @ B^T + bias). 128x128 tile, BK=64, 4 waves, 256 thr.
// Block ordering: chunked XCD swizzle, then group -> msuper(4) -> ny(8) -> mloc(4).
template <int NT>  // K = NT*64
__global__ __launch_bounds__(256) void gemm97_kernel(
    const bf16* __restrict__ Ain, long aAmul,
    const bf16* __restrict__ Bw,
    const float* __restrict__ bias,
    bf16* __restrict__ Cout, long aCmul, int nbm) {
  constexpr int K = NT * 64;
  __shared__ short lsA[128 * 64];
  __shared__ short lsB[128 * 64];
  const int t = threadIdx.x;
  const int nwg = nbm * 128;

  const int flat = blockIdx.x;
  const int perx = nwg >> 3;
  const int swz = (flat & 7) * perx + (flat >> 3);
  const int perg = nbm * 8;
  const int g = swz / perg;
  const int e = swz % perg;
  const int msup = e >> 5;
  const int ny = (e >> 2) & 7;
  const int mloc = e & 3;
  const int mBase = (msup * 4 + mloc) * 128;
  const int nBase = ny * 128;

  const bf16* A0 = Ain + (size_t)g * aAmul;
  const bf16* B0 = Bw + (size_t)g * (1024 * K);
  const float* biasE = bias + g * 1024 + nBase;
  bf16* C0 = Cout + (size_t)g * aCmul + nBase;

  const int w = t >> 6, lane = t & 63;
  const int wm = w >> 1, wn = w & 1;
  const int lr = lane & 15, lk = lane >> 4;

  v4f acc[4][4];
#pragma unroll
  for (int m = 0; m < 4; ++m)
#pragma unroll
    for (int n = 0; n < 4; ++n) acc[m][n] = (v4f)(0.f);

  // T2: pre-swizzled global source granule; LDS dest stays linear.
  const int rowA = t >> 3;                    // 0..31 (row within 32-row group)
  const int sg = (t & 7) ^ (rowA & 7);        // swizzled 16B granule
  const bf16* gA = A0 + (size_t)(mBase + rowA) * K + sg * 8;
  const bf16* gB = B0 + (size_t)(nBase + rowA) * K + sg * 8;

  for (int k0 = 0; k0 < K; k0 += 64) {
#pragma unroll
    for (int i = 0; i < 4; ++i) {
      gload_lds16(gA + (size_t)(i * 32) * K + k0, &lsA[i * 2048 + t * 8]);
      gload_lds16(gB + (size_t)(i * 32) * K + k0, &lsB[i * 2048 + t * 8]);
    }
    __syncthreads();
#pragma unroll
    for (int kk = 0; kk < 2; ++kk) {
      v8s af[4], bfr[4];
#pragma unroll
      for (int m = 0; m < 4; ++m) {
        const int row = wm * 64 + m * 16 + lr;
        af[m] = *(const v8s*)&lsA[row * 64 + ((((kk << 2) + lk) ^ (row & 7)) << 3)];
      }
#pragma unroll
      for (int n = 0; n < 4; ++n) {
        const int row = wn * 64 + n * 16 + lr;
        bfr[n] = *(const v8s*)&lsB[row * 64 + ((((kk << 2) + lk) ^ (row & 7)) << 3)];
      }
#pragma unroll
      for (int m = 0; m < 4; ++m)
#pragma unroll
        for (int n = 0; n < 4; ++n)
          MFMA16(acc[m][n], af[m], bfr[n]);
    }
    __syncthreads();
  }

#pragma unroll
  for (int n = 0; n < 4; ++n) {
    const int colIn = wn * 64 + n * 16 + lr;
    const float bv = biasE[colIn];
#pragma unroll
    for (int m = 0; m < 4; ++m) {
      const int row0 = mBase + wm * 64 + m * 16 + lk * 4;
#pragma unroll
      for (int j = 0; j < 4; ++j) {
        float v = acc[m][n][j] + bv;
        v = v > 0.f ? v : 0.f;
        C0[(size_t)(row0 + j) * 1024 + colIn] = __float2bfloat16(v);
      }
    }
  }
}

// ---------------------------------------------------------------- L3 + softmax + scatter
__global__ __launch_bounds__(256) void gemm2_softmax_kernel(
    const bf16* __restrict__ h1, const bf16* __restrict__ W2b,
    const float* __restrict__ ltl, const int* __restrict__ lidx,
    const int* __restrict__ aidx, float* __restrict__ outp, int mGlobBase, int MC) {
  __shared__ short lsA[2][32 * 64];
  __shared__ short lsB[2][64 * 64];
  __shared__ float X[32][68];
  __shared__ int s_lidx[32];
  __shared__ int s_inv[64];
  __shared__ int s_arow;
  const int a = blockIdx.y;
  const bf16* Ain = h1 + (size_t)a * MC * Hdim;
  const bf16* Bw = W2b + (size_t)a * Pdim * Hdim;
  const float* ltlE = ltl + (size_t)a * Pdim;

  const int t = threadIdx.x;
  const int mBase = blockIdx.x * 32;
  const int w = t >> 6, lane = t & 63;
  const int lr = lane & 15, lk = lane >> 4;
  const int wr = w & 1, wq = w >> 1;

  if (t < 64) s_inv[t] = -1;
  __syncthreads();
  if (t < 32) {
    int q = lidx[t];
    s_lidx[t] = q;
    s_inv[q] = t;
  }
  if (t == 0) s_arow = aidx[a];
  __syncthreads();

  const int srow = t >> 3;
  const int sg = (t & 7) ^ ((t >> 3) & 7);
  const bf16* gA = Ain + (size_t)(mBase + srow) * Hdim + sg * 8;
  const bf16* gB = Bw + (size_t)srow * Hdim + sg * 8;

  auto stage = [&](int buf, int kt) {
    gload_lds16(gA + kt * 64, &lsA[buf][t * 8]);
    gload_lds16(gB + kt * 64, &lsB[buf][t * 8]);
    gload_lds16(gB + (size_t)32 * Hdim + kt * 64, &lsB[buf][2048 + t * 8]);
  };

  v4f acc[2];
  acc[0] = (v4f)(0.f); acc[1] = (v4f)(0.f);

  stage(0, 0);
  for (int kt = 0; kt < 16; ++kt) {
    const int buf = kt & 1;
    if (kt + 1 < 16) { stage(buf ^ 1, kt + 1); WAIT_VM3; } else { WAIT_VM0; }
    BAR();
#pragma unroll
    for (int s = 0; s < 2; ++s) {
      int rowA = wr * 16 + lr;
      v8s af = *(const v8s*)&lsA[buf][rowA * 64 + ((((s << 2) + lk) ^ (rowA & 7)) << 3)];
#pragma unroll
      for (int n = 0; n < 2; ++n) {
        int rowB = wq * 32 + n * 16 + lr;
        v8s bf = *(const v8s*)&lsB[buf][rowB * 64 + ((((s << 2) + lk) ^ (rowB & 7)) << 3)];
        MFMA16(acc[n], af, bf);
      }
    }
    BAR();
  }

#pragma unroll
  for (int n = 0; n < 2; ++n) {
    const int col = wq * 32 + n * 16 + lr;
    const float lc = ltlE[col];
#pragma unroll
    for (int j = 0; j < 4; ++j) {
      X[wr * 16 + lk * 4 + j][col] = acc[n][j] + lc;
    }
  }
  __syncthreads();

  if (t < 32) {
    const int r = t;
    float mx = -1e30f;
#pragma unroll
    for (int l = 0; l < 32; ++l) mx = fmaxf(mx, X[r][s_lidx[l]]);
    float s = 0.f;
#pragma unroll
    for (int l = 0; l < 32; ++l) s += __expf(X[r][s_lidx[l]] - mx);
    const float rs = 1.f / s;
    const size_t obase = ((size_t)(mGlobBase + mBase + r) * 64 + s_arow) * 64;
#pragma unroll
    for (int q0 = 0; q0 < 64; q0 += 4) {
      float4 v;
      v.x = (s_inv[q0 + 0] >= 0) ? __expf(X[r][q0 + 0] - mx) * rs : 0.f;
      v.y = (s_inv[q0 + 1] >= 0) ? __expf(X[r][q0 + 1] - mx) * rs : 0.f;
      v.z = (s_inv[q0 + 2] >= 0) ? __expf(X[r][q0 + 2] - mx) * rs : 0.f;
      v.w = (s_inv[q0 + 3] >= 0) ? __expf(X[r][q0 + 3] - mx) * rs : 0.f;
      *(float4*)&outp[obase + q0] = v;
    }
  }
}

// ---------------------------------------------------------------- launch
extern "C" void kernel_launch(void* const* d_in, const int* in_sizes, int n_in,
                              void* d_out, int out_size, void* d_ws, size_t ws_size,
                              hipStream_t stream) {
  const float* state = (const float*)d_in[0];
  const float* W0 = (const float*)d_in[1];
  const float* b0 = (const float*)d_in[2];
  const float* W1 = (const float*)d_in[3];
  const float* b1 = (const float*)d_in[4];
  const float* W2 = (const float*)d_in[5];
  const float* ltl = (const float*)d_in[6];
  const int* lidx = (const int*)d_in[7];
  const int* aidx = (const int*)d_in[8];
  float* outp = (float*)d_out;

  char* ws = (char*)d_ws;
  bf16* stateb = (bf16*)ws;
  bf16* W0b = stateb + (size_t)Mtot * Fdim;
  bf16* W1b = W0b + (size_t)Aexp * Hdim * Fdim;
  bf16* W2b = W1b + (size_t)Aexp * Hdim * Hdim;
  bf16* h0 = W2b + (size_t)Aexp * Pdim * Hdim;
  const size_t fixedB = (size_t)(Mtot * Fdim + Aexp * Hdim * Fdim +
                                 Aexp * Hdim * Hdim + Aexp * Pdim * Hdim) * 2;
  int MC = 2048;
  while (MC > 512 && fixedB + (size_t)2 * Aexp * MC * Hdim * 2 + 4096 > ws_size) MC >>= 1;
  bf16* h1 = h0 + (size_t)Aexp * MC * Hdim;

  ident_kernel<<<dim3(4096), dim3(256), 0, stream>>>(outp);
  cvt_all_kernel<<<dim3(2048), dim3(256), 0, stream>>>(
      state, (unsigned short*)stateb, Mtot * Fdim / 4,
      W0, (unsigned short*)W0b, Aexp * Hdim * Fdim / 4,
      W1, (unsigned short*)W1b, Aexp * Hdim * Hdim / 4,
      W2, (unsigned short*)W2b, Aexp * Pdim * Hdim / 4);

  const int nbm = MC / 128;
  for (int mOff = 0; mOff < Mtot; mOff += MC) {
    gemm97_kernel<Fdim / 64><<<dim3(nbm * 128), dim3(256), 0, stream>>>(
        stateb + (size_t)mOff * Fdim, 0L,
        W0b, b0, h0, (long)MC * Hdim, nbm);
    gemm97_kernel<Hdim / 64><<<dim3(nbm * 128), dim3(256), 0, stream>>>(
        h0, (long)MC * Hdim,
        W1b, b1, h1, (long)MC * Hdim, nbm);
    gemm2_softmax_kernel<<<dim3(MC / 32, Aexp), dim3(256), 0, stream>>>(
        h1, W2b, ltl, lidx, aidx, outp, mOff, MC);
  }
}